// Round 3
// baseline (357.602 us; speedup 1.0000x reference)
//
#include <hip/hip_runtime.h>

// Problem constants (match reference)
#define Dd 16
#define Zd 64
#define Yd 128
#define Xd 128
#define Cd 2

// Bucketing: tz = i0z>>1 (31 tiles), ty = i0y>>3 (16 tiles)
#define NBUCK_Z 31
#define NBUCK_Y 16
#define NBUCK (NBUCK_Z * NBUCK_Y)   // 496
#define NBUCK_PAD 512

// LDS slab: z-span 5, y-span 11, x rows padded to 134 float2 (12-bank row skew)
#define SZ 5
#define SY 11
#define XPAD2 134                    // row stride in float2 units
#define SLAB_F4 (SZ * SY * 67)       // 67 float4 = 134 float2 per row -> 58960 B

__device__ __forceinline__ void spline_w(float coord, int size, int* idx4, float* w) {
    int i0 = (int)coord;
    float s = coord - (float)i0;
    s = fminf(fmaxf(s, 0.0f), 1.0f);
#pragma unroll
    for (int j = 0; j < 4; ++j) {
        int k = i0 - 1 + j;
        idx4[j] = min(max(k, 0), size - 1);
    }
    float s2 = s * s, s3 = s2 * s;
    w[0] = -0.5f * s3 + s2 - 0.5f * s;
    w[1] =  1.5f * s3 - 2.5f * s2 + 1.0f;
    w[2] = -1.5f * s3 + 2.0f * s2 + 0.5f * s;
    w[3] =  0.5f * s3 - 0.5f * s2;
}

__device__ __forceinline__ int bucket_of(float zc, float yc) {
    int i0z = (int)zc, i0y = (int)yc;
    int tz = min(max(i0z >> 1, 0), NBUCK_Z - 1);
    int ty = min(max(i0y >> 3, 0), NBUCK_Y - 1);
    return tz * NBUCK_Y + ty;
}

// Kernel A: contract depth dim (depth_coord collapses to depth-1 since depths
// are 1..16 consecutive). Also zeroes the bucket counters.
__global__ void depth_contract_kernel(const float* __restrict__ knots,
                                      const float* __restrict__ depth_p,
                                      float4* __restrict__ Wv,
                                      int* __restrict__ counts) {
    const int nv = Zd * Yd * Xd * Cd / 4;
    int t = blockIdx.x * blockDim.x + threadIdx.x;
    if (t < NBUCK_PAD) counts[t] = 0;
    if (t >= nv) return;

    int id[4]; float wd[4];
    spline_w(depth_p[0] - 1.0f, Dd, id, wd);

    const float4* kv = (const float4*)knots;
    const size_t slice = (size_t)Zd * Yd * Xd * Cd / 4;
    float4 a = kv[(size_t)id[0] * slice + t];
    float4 b = kv[(size_t)id[1] * slice + t];
    float4 c = kv[(size_t)id[2] * slice + t];
    float4 d = kv[(size_t)id[3] * slice + t];
    float4 r;
    r.x = wd[0] * a.x + wd[1] * b.x + wd[2] * c.x + wd[3] * d.x;
    r.y = wd[0] * a.y + wd[1] * b.y + wd[2] * c.y + wd[3] * d.y;
    r.z = wd[0] * a.z + wd[1] * b.z + wd[2] * c.z + wd[3] * d.z;
    r.w = wd[0] * a.w + wd[1] * b.w + wd[2] * c.w + wd[3] * d.w;
    Wv[t] = r;
}

// K1: per-bucket histogram
__global__ void hist_kernel(const float* __restrict__ idx, int n_pts,
                            int* __restrict__ counts) {
    int n = blockIdx.x * blockDim.x + threadIdx.x;
    if (n >= n_pts) return;
    atomicAdd(&counts[bucket_of(idx[n * 3], idx[n * 3 + 1])], 1);
}

// K2: exclusive scan (single block of NBUCK_PAD threads), writes offsets+cursors
__global__ __launch_bounds__(NBUCK_PAD) void scan_kernel(const int* __restrict__ counts,
                                                         int* __restrict__ offsets,
                                                         int* __restrict__ cursors) {
    __shared__ int tmp[NBUCK_PAD];
    int t = threadIdx.x;
    int v = counts[t];
    tmp[t] = v;
    __syncthreads();
    for (int off = 1; off < NBUCK_PAD; off <<= 1) {
        int x = (t >= off) ? tmp[t - off] : 0;
        __syncthreads();
        tmp[t] += x;
        __syncthreads();
    }
    int excl = tmp[t] - v;
    offsets[t] = excl;
    cursors[t] = excl;
}

// K3: scatter points into bucket-sorted order; pack coords + orig index as float4
__global__ void scatter_kernel(const float* __restrict__ idx, int n_pts,
                               int* __restrict__ cursors,
                               float4* __restrict__ sorted_pts) {
    int n = blockIdx.x * blockDim.x + threadIdx.x;
    if (n >= n_pts) return;
    float zc = idx[n * 3], yc = idx[n * 3 + 1], xc = idx[n * 3 + 2];
    int pos = atomicAdd(&cursors[bucket_of(zc, yc)], 1);
    float4 sp;
    sp.x = zc; sp.y = yc; sp.z = xc; sp.w = __int_as_float(n);
    sorted_pts[pos] = sp;
}

// K4: one workgroup per bucket. Stage the bucket's W sub-slab into LDS, then
// evaluate all its points from LDS. 4 lanes per point (lane q owns x-tap q).
__global__ __launch_bounds__(256) void bucket_eval_kernel(const float4* __restrict__ sorted_pts,
                                                          const int* __restrict__ offsets,
                                                          const int* __restrict__ counts,
                                                          const float* __restrict__ W,
                                                          float* __restrict__ out) {
    __shared__ float4 slab4[SLAB_F4];
    const int b = blockIdx.x;
    const int tz = b / NBUCK_Y, ty = b - tz * NBUCK_Y;
    const int zbase = min(max(2 * tz - 1, 0), Zd - SZ);
    const int ybase = min(max(8 * ty - 1, 0), Yd - SY);
    const int tid = threadIdx.x;

    // Stage: 55 rows x 64 float4 (256 floats = full x,c row), LDS stride 67 f4
    const float4* Wv4 = (const float4*)W;
    for (int i = tid; i < SZ * SY * 64; i += 256) {
        int r = i >> 6, j = i & 63;
        int dz = r / SY, dy = r - dz * SY;
        slab4[r * 67 + j] = Wv4[(size_t)((zbase + dz) * Yd + (ybase + dy)) * 64 + j];
    }
    __syncthreads();

    const float2* __restrict__ slab2 = (const float2*)slab4;
    const int start = offsets[b];
    const int cnt4 = counts[b] * 4;
    float2* __restrict__ ov = (float2*)out;

    for (int i = tid; i < cnt4; i += 256) {
        int p = i >> 2, q = i & 3;
        float4 sp = sorted_pts[start + p];

        int iz[4], iy[4], ix[4];
        float wz[4], wy[4], wx[4];
        spline_w(sp.x, Zd, iz, wz);
        spline_w(sp.y, Yd, iy, wy);
        spline_w(sp.z, Xd, ix, wx);

        const int ixq = ix[q];
        const float wxq = wx[q];

        float r0 = 0.0f, r1 = 0.0f;
#pragma unroll
        for (int a = 0; a < 4; ++a) {
            const int rz = (iz[a] - zbase) * SY;
#pragma unroll
            for (int bb = 0; bb < 4; ++bb) {
                float2 v = slab2[(rz + (iy[bb] - ybase)) * XPAD2 + ixq];
                float wzy = wz[a] * wy[bb];
                r0 = fmaf(wzy, v.x, r0);
                r1 = fmaf(wzy, v.y, r1);
            }
        }
        r0 *= wxq; r1 *= wxq;
        r0 += __shfl_xor(r0, 1); r0 += __shfl_xor(r0, 2);
        r1 += __shfl_xor(r1, 1); r1 += __shfl_xor(r1, 2);
        if (q == 0) {
            float2 o; o.x = r0; o.y = r1;
            ov[__float_as_int(sp.w)] = o;
        }
    }
}

// Fallbacks (only if ws_size is unexpectedly small)
__global__ void gather_eval_kernel(const float* __restrict__ idx,
                                   const float* __restrict__ W,
                                   float* __restrict__ out, int n_pts) {
    int t = blockIdx.x * blockDim.x + threadIdx.x;
    int n = t >> 2, q = t & 3;
    if (n >= n_pts) return;
    int iz[4], iy[4], ix[4];
    float wz[4], wy[4], wx[4];
    spline_w(idx[n * 3 + 0], Zd, iz, wz);
    spline_w(idx[n * 3 + 1], Yd, iy, wy);
    spline_w(idx[n * 3 + 2], Xd, ix, wx);
    const int ixq = ix[q]; const float wxq = wx[q];
    const float2* Wv = (const float2*)W;
    float r0 = 0.0f, r1 = 0.0f;
#pragma unroll
    for (int a = 0; a < 4; ++a) {
        const int zoff = iz[a] * (Yd * Xd);
#pragma unroll
        for (int bb = 0; bb < 4; ++bb) {
            float2 v = Wv[(size_t)(zoff + iy[bb] * Xd + ixq)];
            float wzy = wz[a] * wy[bb];
            r0 = fmaf(wzy, v.x, r0);
            r1 = fmaf(wzy, v.y, r1);
        }
    }
    r0 *= wxq; r1 *= wxq;
    r0 += __shfl_xor(r0, 1); r0 += __shfl_xor(r0, 2);
    r1 += __shfl_xor(r1, 1); r1 += __shfl_xor(r1, 2);
    if (q == 0) { float2 o; o.x = r0; o.y = r1; ((float2*)out)[n] = o; }
}

__global__ void fused_kernel(const float* __restrict__ idx,
                             const float* __restrict__ knots,
                             const float* __restrict__ depth_p,
                             float* __restrict__ out, int n_pts) {
    int n = blockIdx.x * blockDim.x + threadIdx.x;
    if (n >= n_pts) return;
    int id[4]; float wd[4];
    spline_w(depth_p[0] - 1.0f, Dd, id, wd);
    int iz[4], iy[4], ix[4];
    float wz[4], wy[4], wx[4];
    spline_w(idx[n * 3 + 0], Zd, iz, wz);
    spline_w(idx[n * 3 + 1], Yd, iy, wy);
    spline_w(idx[n * 3 + 2], Xd, ix, wx);
    float acc0 = 0.0f, acc1 = 0.0f;
    for (int dd = 0; dd < 4; ++dd) {
        const float* base = knots + (size_t)id[dd] * Zd * Yd * Xd * Cd;
        float d0 = 0.0f, d1 = 0.0f;
        for (int a = 0; a < 4; ++a)
            for (int bb = 0; bb < 4; ++bb) {
                const float2* row = (const float2*)(base + ((size_t)(iz[a] * Yd + iy[bb]) * Xd) * Cd);
                float r0 = 0.0f, r1 = 0.0f;
                for (int qq = 0; qq < 4; ++qq) {
                    float2 v = row[ix[qq]];
                    r0 = fmaf(wx[qq], v.x, r0);
                    r1 = fmaf(wx[qq], v.y, r1);
                }
                float wzy = wz[a] * wy[bb];
                d0 = fmaf(wzy, r0, d0);
                d1 = fmaf(wzy, r1, d1);
            }
        acc0 = fmaf(wd[dd], d0, acc0);
        acc1 = fmaf(wd[dd], d1, acc1);
    }
    out[n * 2 + 0] = acc0;
    out[n * 2 + 1] = acc1;
}

extern "C" void kernel_launch(void* const* d_in, const int* in_sizes, int n_in,
                              void* d_out, int out_size, void* d_ws, size_t ws_size,
                              hipStream_t stream) {
    const float* idx   = (const float*)d_in[0];
    const float* knots = (const float*)d_in[1];
    const float* depth = (const float*)d_in[2];
    float* out = (float*)d_out;
    const int n_pts = in_sizes[0] / 3;

    const size_t wBytes = (size_t)Zd * Yd * Xd * Cd * sizeof(float);    // 8 MB
    const size_t offCounts  = wBytes;
    const size_t offOffsets = offCounts + NBUCK_PAD * sizeof(int);
    const size_t offCursors = offOffsets + NBUCK_PAD * sizeof(int);
    size_t offSorted = offCursors + NBUCK_PAD * sizeof(int);
    offSorted = (offSorted + 15) & ~(size_t)15;
    const size_t need = offSorted + (size_t)n_pts * sizeof(float4);

    char* ws = (char*)d_ws;
    const int nv = Zd * Yd * Xd * Cd / 4;

    if (ws_size >= need) {
        float* W = (float*)(ws);
        int* counts  = (int*)(ws + offCounts);
        int* offsets = (int*)(ws + offOffsets);
        int* cursors = (int*)(ws + offCursors);
        float4* sorted_pts = (float4*)(ws + offSorted);

        depth_contract_kernel<<<(nv + 255) / 256, 256, 0, stream>>>(knots, depth, (float4*)W, counts);
        hist_kernel<<<(n_pts + 255) / 256, 256, 0, stream>>>(idx, n_pts, counts);
        scan_kernel<<<1, NBUCK_PAD, 0, stream>>>(counts, offsets, cursors);
        scatter_kernel<<<(n_pts + 255) / 256, 256, 0, stream>>>(idx, n_pts, cursors, sorted_pts);
        bucket_eval_kernel<<<NBUCK, 256, 0, stream>>>(sorted_pts, offsets, counts, W, out);
    } else if (ws_size >= wBytes) {
        float* W = (float*)ws;
        depth_contract_kernel<<<(nv + 255) / 256, 256, 0, stream>>>(knots, depth, (float4*)W, (int*)ws /*unused-safe: overwritten by W*/);
        gather_eval_kernel<<<(n_pts * 4 + 255) / 256, 256, 0, stream>>>(idx, W, out, n_pts);
    } else {
        fused_kernel<<<(n_pts + 255) / 256, 256, 0, stream>>>(idx, knots, depth, out, n_pts);
    }
}

// Round 4
// 194.900 us; speedup vs baseline: 1.8348x; 1.8348x over previous
//
#include <hip/hip_runtime.h>

// Problem constants (match reference)
#define Dd 16
#define Zd 64
#define Yd 128
#define Xd 128
#define Cd 2

__device__ __forceinline__ void spline_w(float coord, int size, int* idx4, float* w) {
    int i0 = (int)coord;                       // trunc; coords >= 0 here
    float s = coord - (float)i0;
    s = fminf(fmaxf(s, 0.0f), 1.0f);
#pragma unroll
    for (int j = 0; j < 4; ++j) {
        int k = i0 - 1 + j;
        idx4[j] = min(max(k, 0), size - 1);
    }
    float s2 = s * s, s3 = s2 * s;
    // Catmull-Rom weights (powers @ HERMITE @ CR)
    w[0] = -0.5f * s3 + s2 - 0.5f * s;
    w[1] =  1.5f * s3 - 2.5f * s2 + 1.0f;
    w[2] = -1.5f * s3 + 2.0f * s2 + 0.5f * s;
    w[3] =  0.5f * s3 - 0.5f * s2;
}

// Round-to-nearest-even f32 -> bf16, packed (a in low 16, b in high 16)
__device__ __forceinline__ unsigned pack_bf16x2(float a, float b) {
    unsigned ua = __float_as_uint(a);
    unsigned ub = __float_as_uint(b);
    ua += 0x7fffu + ((ua >> 16) & 1u);
    ub += 0x7fffu + ((ub >> 16) & 1u);
    return (ua >> 16) | (ub & 0xffff0000u);
}

// Kernel A: contract depth dim into a bf16 volume.
// depths = arange(1,17) => searchsorted+lerp collapses to depth_coord = depth-1.
// W_bf16[z][y][x] = packed (ch0, ch1). 4 MB total -> fits every XCD's 4 MB L2.
__global__ void depth_contract_bf16_kernel(const float* __restrict__ knots,
                                           const float* __restrict__ depth_p,
                                           uint4* __restrict__ Wv) {
    const int nv8 = Zd * Yd * Xd * Cd / 8;     // 262144 threads, 8 floats each
    int t = blockIdx.x * blockDim.x + threadIdx.x;
    if (t >= nv8) return;

    int id[4]; float wd[4];
    spline_w(depth_p[0] - 1.0f, Dd, id, wd);

    const float4* kv = (const float4*)knots;
    const size_t slice4 = (size_t)Zd * Yd * Xd * Cd / 4;   // float4 per depth slice
    const size_t base = (size_t)t * 2;

    float4 r0 = make_float4(0.f, 0.f, 0.f, 0.f);
    float4 r1 = make_float4(0.f, 0.f, 0.f, 0.f);
#pragma unroll
    for (int j = 0; j < 4; ++j) {
        const float4* sp = kv + (size_t)id[j] * slice4 + base;
        float4 a = sp[0];
        float4 b = sp[1];
        float wj = wd[j];
        r0.x = fmaf(wj, a.x, r0.x); r0.y = fmaf(wj, a.y, r0.y);
        r0.z = fmaf(wj, a.z, r0.z); r0.w = fmaf(wj, a.w, r0.w);
        r1.x = fmaf(wj, b.x, r1.x); r1.y = fmaf(wj, b.y, r1.y);
        r1.z = fmaf(wj, b.z, r1.z); r1.w = fmaf(wj, b.w, r1.w);
    }
    uint4 o;
    o.x = pack_bf16x2(r0.x, r0.y);   // (ch0,ch1) at x0
    o.y = pack_bf16x2(r0.z, r0.w);   // x1
    o.z = pack_bf16x2(r1.x, r1.y);   // x2
    o.w = pack_bf16x2(r1.z, r1.w);   // x3
    Wv[t] = o;
}

// Kernel B: 4 lanes per point; lane q owns x-tap q. Each lane does 16
// independent 4B loads (one packed bf16x2 = both channels of one tap).
// A quad's 4 lanes cover a contiguous 16B row. W is 4 MB -> L2-resident.
__global__ void gather_eval_bf16_kernel(const float* __restrict__ idx,
                                        const unsigned* __restrict__ W,
                                        float* __restrict__ out, int n_pts) {
    int t = blockIdx.x * blockDim.x + threadIdx.x;
    int n = t >> 2;            // point index
    int q = t & 3;             // x-tap
    if (n >= n_pts) return;

    float zc = idx[n * 3 + 0];
    float yc = idx[n * 3 + 1];
    float xc = idx[n * 3 + 2];

    int iz[4], iy[4], ix[4];
    float wz[4], wy[4], wx[4];
    spline_w(zc, Zd, iz, wz);
    spline_w(yc, Yd, iy, wy);
    spline_w(xc, Xd, ix, wx);

    const int ixq = ix[q];
    const float wxq = wx[q];

    float r0 = 0.0f, r1 = 0.0f;
#pragma unroll
    for (int a = 0; a < 4; ++a) {
        const int zoff = iz[a] * (Yd * Xd);
#pragma unroll
        for (int b = 0; b < 4; ++b) {
            unsigned w = W[zoff + iy[b] * Xd + ixq];
            float c0 = __uint_as_float(w << 16);
            float c1 = __uint_as_float(w & 0xffff0000u);
            float wzy = wz[a] * wy[b];
            r0 = fmaf(wzy, c0, r0);
            r1 = fmaf(wzy, c1, r1);
        }
    }
    r0 *= wxq;
    r1 *= wxq;

    // Reduce across the quad
    r0 += __shfl_xor(r0, 1); r0 += __shfl_xor(r0, 2);
    r1 += __shfl_xor(r1, 1); r1 += __shfl_xor(r1, 2);

    if (q == 0) {
        float2 o; o.x = r0; o.y = r1;
        ((float2*)out)[n] = o;
    }
}

// Fallback: fully fused f32 (used only if d_ws can't hold the 4 MB volume).
__global__ void fused_kernel(const float* __restrict__ idx,
                             const float* __restrict__ knots,
                             const float* __restrict__ depth_p,
                             float* __restrict__ out, int n_pts) {
    int n = blockIdx.x * blockDim.x + threadIdx.x;
    if (n >= n_pts) return;
    int id[4]; float wd[4];
    spline_w(depth_p[0] - 1.0f, Dd, id, wd);
    int iz[4], iy[4], ix[4];
    float wz[4], wy[4], wx[4];
    spline_w(idx[n * 3 + 0], Zd, iz, wz);
    spline_w(idx[n * 3 + 1], Yd, iy, wy);
    spline_w(idx[n * 3 + 2], Xd, ix, wx);
    float acc0 = 0.0f, acc1 = 0.0f;
    for (int dd = 0; dd < 4; ++dd) {
        const float* base = knots + (size_t)id[dd] * Zd * Yd * Xd * Cd;
        float d0 = 0.0f, d1 = 0.0f;
        for (int a = 0; a < 4; ++a)
            for (int bb = 0; bb < 4; ++bb) {
                const float2* row = (const float2*)(base + ((size_t)(iz[a] * Yd + iy[bb]) * Xd) * Cd);
                float r0 = 0.0f, r1 = 0.0f;
                for (int qq = 0; qq < 4; ++qq) {
                    float2 v = row[ix[qq]];
                    r0 = fmaf(wx[qq], v.x, r0);
                    r1 = fmaf(wx[qq], v.y, r1);
                }
                float wzy = wz[a] * wy[bb];
                d0 = fmaf(wzy, r0, d0);
                d1 = fmaf(wzy, r1, d1);
            }
        acc0 = fmaf(wd[dd], d0, acc0);
        acc1 = fmaf(wd[dd], d1, acc1);
    }
    out[n * 2 + 0] = acc0;
    out[n * 2 + 1] = acc1;
}

extern "C" void kernel_launch(void* const* d_in, const int* in_sizes, int n_in,
                              void* d_out, int out_size, void* d_ws, size_t ws_size,
                              hipStream_t stream) {
    const float* idx   = (const float*)d_in[0];   // [N,3] f32
    const float* knots = (const float*)d_in[1];   // [16,64,128,128,2] f32
    const float* depth = (const float*)d_in[2];   // scalar f32
    float* out = (float*)d_out;                   // [N,2] f32
    const int n_pts = in_sizes[0] / 3;

    const size_t wBytes = (size_t)Zd * Yd * Xd * Cd * 2;   // 4 MB bf16
    if (ws_size >= wBytes) {
        unsigned* W = (unsigned*)d_ws;
        const int nv8 = Zd * Yd * Xd * Cd / 8;
        depth_contract_bf16_kernel<<<(nv8 + 255) / 256, 256, 0, stream>>>(knots, depth, (uint4*)W);
        const int nthreads = n_pts * 4;
        gather_eval_bf16_kernel<<<(nthreads + 255) / 256, 256, 0, stream>>>(idx, W, out, n_pts);
    } else {
        fused_kernel<<<(n_pts + 255) / 256, 256, 0, stream>>>(idx, knots, depth, out, n_pts);
    }
}